// Round 11
// baseline (961.003 us; speedup 1.0000x reference)
//
#include <hip/hip_runtime.h>
#include <math.h>

#define BATCH 16
#define IN 128
#define HD 32
#define NN 2048
#define NE 32768
#define SEQ 100
#define TPB 512
#define NBLK 512            // 2 blocks/CU -- PROVEN co-resident (rounds 6-10); do not raise
#define GSZ 32              // global barrier: blocks per group
#define NGRP (NBLK / GSZ)   // 16
#define NXCD 8
#define MAXJ 64             // max (k,wave) node slots per block
#define ECAP 1536           // LDS edge cache entries (int2, 12 KB)
#define STEPB (NN * HD * 4) // byte stride of one timestep slice of one batch

// ---------------- preprocessing ----------------

__global__ void count_deg(const int* __restrict__ src, const int* __restrict__ dst,
                          int* deg_out, int* deg_in) {
    int e = blockIdx.x * blockDim.x + threadIdx.x;
    if (e < NE) {
        atomicAdd(&deg_out[src[e]], 1);
        atomicAdd(&deg_in[dst[e]], 1);
    }
}

__global__ void scan_rowptr(const int* __restrict__ deg_in, int* __restrict__ row_ptr) {
    __shared__ int partial[256];
    int t = threadIdx.x;
    int base = t * 8;
    int vals[8];
    int s = 0;
    for (int j = 0; j < 8; j++) { vals[j] = deg_in[base + j]; s += vals[j]; }
    partial[t] = s;
    __syncthreads();
    if (t == 0) {
        int acc = 0;
        for (int i = 0; i < 256; i++) { int v = partial[i]; partial[i] = acc; acc += v; }
        row_ptr[NN] = acc;
    }
    __syncthreads();
    int acc = partial[t];
    for (int j = 0; j < 8; j++) { row_ptr[base + j] = acc; acc += vals[j]; }
}

// col_idx stores src*HD (element offset of the source node's row)
__global__ void scatter_edges(const int* __restrict__ src, const int* __restrict__ dst,
                              const int* __restrict__ deg_out, const int* __restrict__ deg_in,
                              const int* __restrict__ row_ptr, int* __restrict__ cursor,
                              int* __restrict__ col_idx, float* __restrict__ wgt) {
    int e = blockIdx.x * blockDim.x + threadIdx.x;
    if (e < NE) {
        int s = src[e], d = dst[e];
        int pos = row_ptr[d] + atomicAdd(&cursor[d], 1);
        col_idx[pos] = s * HD;
        float doo = (float)max(deg_out[s], 1);
        float dii = (float)max(deg_in[d], 1);
        wgt[pos] = rsqrtf(doo * dii);
    }
}

__global__ void xgates(const float* __restrict__ x,
                       const float* __restrict__ Wr, const float* __restrict__ br,
                       const float* __restrict__ Wz, const float* __restrict__ bz,
                       const float* __restrict__ Wh, const float* __restrict__ bh,
                       float* __restrict__ xr, float* __restrict__ xz, float* __restrict__ xh) {
    int t = blockIdx.x * blockDim.x + threadIdx.x;
    if (t < BATCH * HD) {
        int b = t / HD, hh = t % HD;
        float ar = br[hh], az = bz[hh], ah = bh[hh];
        const float* xb = x + b * IN;
        for (int i = 0; i < IN; i++) {
            float xv = xb[i];
            ar += xv * Wr[i * HD + hh];
            az += xv * Wz[i * HD + hh];
            ah += xv * Wh[i * HD + hh];
        }
        xr[t] = ar; xz[t] = az; xh[t] = ah;
    }
}

// ---------------- barriers ----------------

// Global two-level barrier with agent fences (proven round 6).
__device__ __forceinline__ void global_barrier(unsigned* __restrict__ lvl1,
                                               unsigned* __restrict__ root,
                                               unsigned step) {
    __syncthreads();
    if (threadIdx.x == 0) {
        const int gid = blockIdx.x / GSZ;
        __builtin_amdgcn_fence(__ATOMIC_RELEASE, "agent");
        __hip_atomic_fetch_add(&lvl1[gid * 32], 1u, __ATOMIC_RELAXED,
                               __HIP_MEMORY_SCOPE_AGENT);
        if ((blockIdx.x % GSZ) == 0) {
            while (__hip_atomic_load(&lvl1[gid * 32], __ATOMIC_RELAXED,
                                     __HIP_MEMORY_SCOPE_AGENT) < GSZ * step)
                __builtin_amdgcn_s_sleep(2);
            __hip_atomic_fetch_add(root, 1u, __ATOMIC_RELAXED,
                                   __HIP_MEMORY_SCOPE_AGENT);
        }
        while (__hip_atomic_load(root, __ATOMIC_RELAXED,
                                 __HIP_MEMORY_SCOPE_AGENT) < NGRP * step)
            __builtin_amdgcn_s_sleep(2);
        __builtin_amdgcn_fence(__ATOMIC_ACQUIRE, "agent");
    }
    __syncthreads();
}

// Per-XCD barrier (proven rounds 7-10). Arrivals spread over 8 cache lines
// (slot&7); leader polls the 8-line sum (monotonic counters -> race-free).
__device__ __forceinline__ void xcd_barrier(unsigned* __restrict__ xcnt,
                                            unsigned* __restrict__ xgo,
                                            int xid, int slot, int cnt, unsigned s) {
    __syncthreads();
    if (threadIdx.x == 0) {
        __hip_atomic_fetch_add(&xcnt[(xid * 8 + (slot & 7)) * 32], 1u,
                               __ATOMIC_RELAXED, __HIP_MEMORY_SCOPE_AGENT);
        if (slot == 0) {
            for (;;) {
                unsigned sum = 0;
#pragma unroll
                for (int i = 0; i < 8; i++)
                    sum += __hip_atomic_load(&xcnt[(xid * 8 + i) * 32],
                                             __ATOMIC_RELAXED, __HIP_MEMORY_SCOPE_AGENT);
                if (sum >= (unsigned)cnt * s) break;
                __builtin_amdgcn_s_sleep(1);
            }
            __hip_atomic_store(&xgo[xid * 32], s, __ATOMIC_RELAXED,
                               __HIP_MEMORY_SCOPE_AGENT);
        } else {
            while (__hip_atomic_load(&xgo[xid * 32], __ATOMIC_RELAXED,
                                     __HIP_MEMORY_SCOPE_AGENT) < s)
                __builtin_amdgcn_s_sleep(1);
        }
    }
    __syncthreads();
    asm volatile("buffer_inv sc0\n\ts_waitcnt vmcnt(0)" ::: "memory");
}

// ---------------- persistent kernel ----------------
// Recurrent state lives IN the output array: step t reads out[b][t-1][*][*].
// Wave = one node for a batch PAIR: lanes 0-31 -> batch b0, lanes 32-63 -> b0+1.

__device__ __forceinline__ float fast_sigmoid(float x) {
    return __builtin_amdgcn_rcpf(1.f + __expf(-x));
}

__global__ void __launch_bounds__(TPB) gru_persistent(
    const int* __restrict__ row_ptr, const int* __restrict__ col_idx,
    const float* __restrict__ wgt,
    const float* __restrict__ Wg, const float* __restrict__ bg,
    const float* __restrict__ xr, const float* __restrict__ xz,
    const float* __restrict__ xh,
    float* __restrict__ out,
    unsigned* __restrict__ glvl1, unsigned* __restrict__ groot,
    unsigned* __restrict__ xreg, unsigned* __restrict__ xcnt,
    unsigned* __restrict__ xgo)
{
    __shared__ float aggL[TPB];
    __shared__ int jn[MAXJ], jrs[MAXJ], jraw[MAXJ], jplen[MAXJ], jofs[MAXJ];
    __shared__ __align__(16) int2 eLDS[ECAP];   // (byte-offset, bitcast weight)
    __shared__ int shr_slot, shr_cnt, shr_mode, shr_use;

    const int tid = threadIdx.x;
    const int lane = tid & 63;
    const int wid = tid >> 6;        // wave id (0..7)
    const int half = lane >> 5;      // which batch of the pair
    const int l = lane & 31;         // channel

    // physical XCD id [measured: learn_hip m09]
    int xraw;
    asm volatile("s_getreg_b32 %0, hwreg(HW_REG_XCC_ID)" : "=s"(xraw));
    int xid = xraw & 7;

    if (tid == 0)
        shr_slot = (int)__hip_atomic_fetch_add(&xreg[xid * 32], 1u, __ATOMIC_RELAXED,
                                               __HIP_MEMORY_SCOPE_AGENT);
    __syncthreads();
    int slot = shr_slot;

    global_barrier(glvl1, groot, 1u);   // settle registration

    if (tid == 0) {
        int sum = 0, mode = 1, mycnt = 0;
        for (int xx = 0; xx < NXCD; xx++) {
            int c = (int)__hip_atomic_load(&xreg[xx * 32], __ATOMIC_RELAXED,
                                           __HIP_MEMORY_SCOPE_AGENT);
            sum += c;
            if (c < 32) mode = 0;       // guarantees nodes/wave <= 8 (MAXJ)
            if (xx == xid) mycnt = c;
        }
        if (sum != NBLK) mode = 0;
        shr_mode = mode;
        shr_cnt = mycnt;
    }
    __syncthreads();
    const int xmode = shr_mode;
    int cnt = shr_cnt;
    if (!xmode) { xid = blockIdx.x & 7; slot = blockIdx.x >> 3; cnt = NBLK / NXCD; }
    const int wtot = cnt * 8;

    // ---- per-block node metadata (j = k*8 + waveid) ----
    if (tid < MAXJ) {
        int k = tid >> 3, w = tid & 7;
        int n = slot * 8 + w + k * wtot;
        if (n < NN) {
            int rs = row_ptr[n], re = row_ptr[n + 1];
            jn[tid] = n; jrs[tid] = rs; jraw[tid] = re - rs;
            jplen[tid] = (re - rs + 1) & ~1;            // pad to x2 (int4 granule)
        } else {
            jn[tid] = -1; jrs[tid] = 0; jraw[tid] = 0; jplen[tid] = 0;
        }
    }
    __syncthreads();
    if (tid == 0) {
        int o = 0;
        for (int j = 0; j < MAXJ; j++) { jofs[j] = o; o += jplen[j]; }
        shr_use = (o <= ECAP);
    }
    __syncthreads();
    const bool use_lds = (shr_use != 0);

    // ---- stage edges into LDS once (time-invariant), padded to x2 ----
    if (use_lds) {
        for (int k = 0; k < 8; k++) {
            int j = k * 8 + wid;
            if (jn[j] < 0) break;
            int rs = jrs[j], raw = jraw[j], pl = jplen[j], of = jofs[j];
            for (int i = lane; i < pl; i += 64) {
                int2 v;
                if (i < raw) { v.x = col_idx[rs + i] << 2; v.y = __float_as_int(wgt[rs + i]); }
                else         { v.x = 0; v.y = 0; }
                eLDS[of + i] = v;
            }
        }
    }
    __syncthreads();

    // ---- per-thread constants ----
    const int bb = 2 * xid + half;
    const float xrv = xr[bb * HD + l];
    const float xzv = xz[bb * HD + l];
    const float xhv = xh[bb * HD + l];
    const float bgv = bg[l];
    float wgreg[HD];
#pragma unroll
    for (int k = 0; k < HD; k++) wgreg[k] = Wg[k * HD + l];

    char* const outc = (char*)out;
    // byte offset of (batch bb, step 0, node 0, channel l)
    unsigned ocur = (unsigned)(bb * SEQ) * STEPB + (unsigned)(l * 4);

    // ---- t = 0: state is identically zero -> no gather, no matvec ----
    {
        const float conv = bgv;
        const float z = fast_sigmoid(xzv + conv);
        const float e2 = __expf(2.f * (xhv + fast_sigmoid(xrv + conv) * conv));
        const float ht = 1.f - 2.f * __builtin_amdgcn_rcpf(e2 + 1.f);
        const float hn = z * ht;                        // hp = 0
        for (int k = 0; k < 8; k++) {
            const int n = jn[k * 8 + wid];
            if (n < 0) break;
            *(float*)(outc + (ocur + ((unsigned)n << 7))) = hn;
        }
    }
    if (xmode) xcd_barrier(xcnt, xgo, xid, slot, cnt, 1u);
    else       global_barrier(glvl1, groot, 2u);
    ocur += STEPB;

    for (int t = 1; t < SEQ; t++) {
        const char* opc = outc + (ocur - STEPB);        // previous step slice
        for (int k = 0; k < 8; k++) {
            const int j = k * 8 + wid;
            const int n = jn[j];
            if (n < 0) break;

            float agg = 0.f;
            if (use_lds) {
                const int4* ep = (const int4*)&eLDS[jofs[j]];   // 2 edges per int4
                const int pl = jplen[j];
                int e = 0;
                for (; e + 16 <= pl; e += 16) {
                    int4 p0 = ep[0], p1 = ep[1], p2 = ep[2], p3 = ep[3];
                    int4 p4 = ep[4], p5 = ep[5], p6 = ep[6], p7 = ep[7];
                    ep += 8;
                    float v0 = *(const float*)(opc + (unsigned)p0.x);
                    float v1 = *(const float*)(opc + (unsigned)p0.z);
                    float v2 = *(const float*)(opc + (unsigned)p1.x);
                    float v3 = *(const float*)(opc + (unsigned)p1.z);
                    float v4 = *(const float*)(opc + (unsigned)p2.x);
                    float v5 = *(const float*)(opc + (unsigned)p2.z);
                    float v6 = *(const float*)(opc + (unsigned)p3.x);
                    float v7 = *(const float*)(opc + (unsigned)p3.z);
                    float v8 = *(const float*)(opc + (unsigned)p4.x);
                    float v9 = *(const float*)(opc + (unsigned)p4.z);
                    float va = *(const float*)(opc + (unsigned)p5.x);
                    float vb = *(const float*)(opc + (unsigned)p5.z);
                    float vc = *(const float*)(opc + (unsigned)p6.x);
                    float vd = *(const float*)(opc + (unsigned)p6.z);
                    float ve = *(const float*)(opc + (unsigned)p7.x);
                    float vf = *(const float*)(opc + (unsigned)p7.z);
                    agg = fmaf(__int_as_float(p0.y), v0, agg);
                    agg = fmaf(__int_as_float(p0.w), v1, agg);
                    agg = fmaf(__int_as_float(p1.y), v2, agg);
                    agg = fmaf(__int_as_float(p1.w), v3, agg);
                    agg = fmaf(__int_as_float(p2.y), v4, agg);
                    agg = fmaf(__int_as_float(p2.w), v5, agg);
                    agg = fmaf(__int_as_float(p3.y), v6, agg);
                    agg = fmaf(__int_as_float(p3.w), v7, agg);
                    agg = fmaf(__int_as_float(p4.y), v8, agg);
                    agg = fmaf(__int_as_float(p4.w), v9, agg);
                    agg = fmaf(__int_as_float(p5.y), va, agg);
                    agg = fmaf(__int_as_float(p5.w), vb, agg);
                    agg = fmaf(__int_as_float(p6.y), vc, agg);
                    agg = fmaf(__int_as_float(p6.w), vd, agg);
                    agg = fmaf(__int_as_float(p7.y), ve, agg);
                    agg = fmaf(__int_as_float(p7.w), vf, agg);
                }
                for (; e < pl; e += 2) {                 // 2-edge tail granules
                    int4 p0 = *ep++;
                    float v0 = *(const float*)(opc + (unsigned)p0.x);
                    float v1 = *(const float*)(opc + (unsigned)p0.z);
                    agg = fmaf(__int_as_float(p0.y), v0, agg);
                    agg = fmaf(__int_as_float(p0.w), v1, agg);
                }
            } else {   // rare overflow path: stream edge list from global
                const int rs = jrs[j], re = rs + jraw[j];
                for (int e = rs; e < re; e++) {
                    unsigned cb = (unsigned)col_idx[e] << 2;
                    agg = fmaf(wgt[e], *(const float*)(opc + cb), agg);
                }
            }

            // matvec: conv[l] = bg[l] + sum_k agg[k] * Wg[k][l]
            // per-wave LDS broadcast (writer wave == reader wave -> lockstep)
            aggL[tid] = agg;
            const float4* arow = (const float4*)&aggL[(tid & ~63) + (half << 5)];
            float conv = bgv;
#pragma unroll
            for (int kq = 0; kq < 8; kq++) {
                float4 a4 = arow[kq];
                conv = fmaf(a4.x, wgreg[4 * kq + 0], conv);
                conv = fmaf(a4.y, wgreg[4 * kq + 1], conv);
                conv = fmaf(a4.z, wgreg[4 * kq + 2], conv);
                conv = fmaf(a4.w, wgreg[4 * kq + 3], conv);
            }

            const float r = fast_sigmoid(xrv + conv);
            const float z = fast_sigmoid(xzv + conv);
            const float e2 = __expf(2.f * (xhv + r * conv));
            const float ht = 1.f - 2.f * __builtin_amdgcn_rcpf(e2 + 1.f);
            const unsigned nb = (unsigned)n << 7;        // node byte offset in slice
            const float hp = *(const float*)(opc + nb);
            const float hn = fmaf(z, ht - hp, hp);

            *(float*)(outc + (ocur + nb)) = hn;
        }
        if (t != SEQ - 1) {
            if (xmode) xcd_barrier(xcnt, xgo, xid, slot, cnt, (unsigned)(t + 1));
            else       global_barrier(glvl1, groot, (unsigned)(t + 2));
        }
        ocur += STEPB;
    }
}

// ---------------- launch ----------------

extern "C" void kernel_launch(void* const* d_in, const int* in_sizes, int n_in,
                              void* d_out, int out_size, void* d_ws, size_t ws_size,
                              hipStream_t stream) {
    const float* x   = (const float*)d_in[0];
    const int*   src = (const int*)d_in[1];
    const int*   dst = (const int*)d_in[2];
    const float* Wr  = (const float*)d_in[3];
    const float* br  = (const float*)d_in[4];
    const float* Wz  = (const float*)d_in[5];
    const float* bz  = (const float*)d_in[6];
    const float* Wh  = (const float*)d_in[7];
    const float* bh  = (const float*)d_in[8];
    const float* Wg  = (const float*)d_in[9];
    const float* bg  = (const float*)d_in[10];
    float* out = (float*)d_out;

    char* ws = (char*)d_ws;
    float* xr = (float*)ws;            ws += BATCH * HD * 4;
    float* xz = (float*)ws;            ws += BATCH * HD * 4;
    float* xh = (float*)ws;            ws += BATCH * HD * 4;
    int* deg_out = (int*)ws;           ws += NN * 4;
    int* deg_in  = (int*)ws;           ws += NN * 4;
    int* cursor  = (int*)ws;           ws += NN * 4;
    int* row_ptr = (int*)ws;           ws += (NN + 1) * 4;
    int* col_idx = (int*)ws;           ws += NE * 4;
    float* wgt   = (float*)ws;         ws += NE * 4;
    unsigned* glvl1 = (unsigned*)ws;   ws += NGRP * 32 * 4;
    unsigned* groot = (unsigned*)ws;   ws += 32 * 4;
    unsigned* xreg  = (unsigned*)ws;   ws += NXCD * 32 * 4;
    unsigned* xcnt  = (unsigned*)ws;   ws += NXCD * 8 * 32 * 4;
    unsigned* xgo   = (unsigned*)ws;   ws += NXCD * 32 * 4;

    hipMemsetAsync(deg_out, 0, 3 * NN * 4, stream);
    hipMemsetAsync(glvl1, 0,
                   (NGRP * 32 + 32 + NXCD * 32 + NXCD * 8 * 32 + NXCD * 32) * 4, stream);

    count_deg<<<NE / 256, 256, 0, stream>>>(src, dst, deg_out, deg_in);
    scan_rowptr<<<1, 256, 0, stream>>>(deg_in, row_ptr);
    scatter_edges<<<NE / 256, 256, 0, stream>>>(src, dst, deg_out, deg_in, row_ptr,
                                                cursor, col_idx, wgt);
    xgates<<<2, 256, 0, stream>>>(x, Wr, br, Wz, bz, Wh, bh, xr, xz, xh);

    gru_persistent<<<dim3(NBLK), dim3(TPB), 0, stream>>>(
        row_ptr, col_idx, wgt, Wg, bg, xr, xz, xh, out,
        glvl1, groot, xreg, xcnt, xgo);
}

// Round 12
// 894.174 us; speedup vs baseline: 1.0747x; 1.0747x over previous
//
#include <hip/hip_runtime.h>
#include <math.h>

#define BATCH 16
#define IN 128
#define HD 32
#define NN 2048
#define NE 32768
#define SEQ 100
#define TPB 512
#define NBLK 512            // 2 blocks/CU -- PROVEN co-resident (rounds 6-10); do not raise
#define GSZ 32              // global barrier: blocks per group
#define NGRP (NBLK / GSZ)   // 16
#define NXCD 8
#define MAXJ 64             // max (k,wave) node slots per block
#define ECAP 1536           // LDS edge cache entries (int2, 12 KB)

// ---------------- preprocessing ----------------

__global__ void count_deg(const int* __restrict__ src, const int* __restrict__ dst,
                          int* deg_out, int* deg_in) {
    int e = blockIdx.x * blockDim.x + threadIdx.x;
    if (e < NE) {
        atomicAdd(&deg_out[src[e]], 1);
        atomicAdd(&deg_in[dst[e]], 1);
    }
}

__global__ void scan_rowptr(const int* __restrict__ deg_in, int* __restrict__ row_ptr) {
    __shared__ int partial[256];
    int t = threadIdx.x;
    int base = t * 8;
    int vals[8];
    int s = 0;
    for (int j = 0; j < 8; j++) { vals[j] = deg_in[base + j]; s += vals[j]; }
    partial[t] = s;
    __syncthreads();
    if (t == 0) {
        int acc = 0;
        for (int i = 0; i < 256; i++) { int v = partial[i]; partial[i] = acc; acc += v; }
        row_ptr[NN] = acc;
    }
    __syncthreads();
    int acc = partial[t];
    for (int j = 0; j < 8; j++) { row_ptr[base + j] = acc; acc += vals[j]; }
}

// col_idx stores src*HD (element offset of the source node's row)
__global__ void scatter_edges(const int* __restrict__ src, const int* __restrict__ dst,
                              const int* __restrict__ deg_out, const int* __restrict__ deg_in,
                              const int* __restrict__ row_ptr, int* __restrict__ cursor,
                              int* __restrict__ col_idx, float* __restrict__ wgt) {
    int e = blockIdx.x * blockDim.x + threadIdx.x;
    if (e < NE) {
        int s = src[e], d = dst[e];
        int pos = row_ptr[d] + atomicAdd(&cursor[d], 1);
        col_idx[pos] = s * HD;
        float doo = (float)max(deg_out[s], 1);
        float dii = (float)max(deg_in[d], 1);
        wgt[pos] = rsqrtf(doo * dii);
    }
}

__global__ void xgates(const float* __restrict__ x,
                       const float* __restrict__ Wr, const float* __restrict__ br,
                       const float* __restrict__ Wz, const float* __restrict__ bz,
                       const float* __restrict__ Wh, const float* __restrict__ bh,
                       float* __restrict__ xr, float* __restrict__ xz, float* __restrict__ xh) {
    int t = blockIdx.x * blockDim.x + threadIdx.x;
    if (t < BATCH * HD) {
        int b = t / HD, hh = t % HD;
        float ar = br[hh], az = bz[hh], ah = bh[hh];
        const float* xb = x + b * IN;
        for (int i = 0; i < IN; i++) {
            float xv = xb[i];
            ar += xv * Wr[i * HD + hh];
            az += xv * Wz[i * HD + hh];
            ah += xv * Wh[i * HD + hh];
        }
        xr[t] = ar; xz[t] = az; xh[t] = ah;
    }
}

// ---------------- barriers ----------------

// Global two-level barrier with agent fences (proven round 6).
__device__ __forceinline__ void global_barrier(unsigned* __restrict__ lvl1,
                                               unsigned* __restrict__ root,
                                               unsigned step) {
    __syncthreads();
    if (threadIdx.x == 0) {
        const int gid = blockIdx.x / GSZ;
        __builtin_amdgcn_fence(__ATOMIC_RELEASE, "agent");
        __hip_atomic_fetch_add(&lvl1[gid * 32], 1u, __ATOMIC_RELAXED,
                               __HIP_MEMORY_SCOPE_AGENT);
        if ((blockIdx.x % GSZ) == 0) {
            while (__hip_atomic_load(&lvl1[gid * 32], __ATOMIC_RELAXED,
                                     __HIP_MEMORY_SCOPE_AGENT) < GSZ * step)
                __builtin_amdgcn_s_sleep(2);
            __hip_atomic_fetch_add(root, 1u, __ATOMIC_RELAXED,
                                   __HIP_MEMORY_SCOPE_AGENT);
        }
        while (__hip_atomic_load(root, __ATOMIC_RELAXED,
                                 __HIP_MEMORY_SCOPE_AGENT) < NGRP * step)
            __builtin_amdgcn_s_sleep(2);
        __builtin_amdgcn_fence(__ATOMIC_ACQUIRE, "agent");
    }
    __syncthreads();
}

// Per-XCD barrier (proven rounds 7-10). Arrivals spread over 8 cache lines
// (slot&7); leader polls the 8-line sum (monotonic counters -> race-free).
__device__ __forceinline__ void xcd_barrier(unsigned* __restrict__ xcnt,
                                            unsigned* __restrict__ xgo,
                                            int xid, int slot, int cnt, unsigned s) {
    __syncthreads();
    if (threadIdx.x == 0) {
        __hip_atomic_fetch_add(&xcnt[(xid * 8 + (slot & 7)) * 32], 1u,
                               __ATOMIC_RELAXED, __HIP_MEMORY_SCOPE_AGENT);
        if (slot == 0) {
            for (;;) {
                unsigned sum = 0;
#pragma unroll
                for (int i = 0; i < 8; i++)
                    sum += __hip_atomic_load(&xcnt[(xid * 8 + i) * 32],
                                             __ATOMIC_RELAXED, __HIP_MEMORY_SCOPE_AGENT);
                if (sum >= (unsigned)cnt * s) break;
                __builtin_amdgcn_s_sleep(1);
            }
            __hip_atomic_store(&xgo[xid * 32], s, __ATOMIC_RELAXED,
                               __HIP_MEMORY_SCOPE_AGENT);
        } else {
            while (__hip_atomic_load(&xgo[xid * 32], __ATOMIC_RELAXED,
                                     __HIP_MEMORY_SCOPE_AGENT) < s)
                __builtin_amdgcn_s_sleep(1);
        }
    }
    __syncthreads();
    asm volatile("buffer_inv sc0\n\ts_waitcnt vmcnt(0)" ::: "memory");
}

// ---------------- persistent kernel ----------------
// h layout: [B][N][H] in a compact 4MB double buffer (stays L2-resident --
// round 11 proved using `out` as state costs 200MB of HBM re-fetch).
// Wave = one node for a batch PAIR: lanes 0-31 -> batch b0, lanes 32-63 -> b0+1.

__device__ __forceinline__ float fast_sigmoid(float x) {
    return __builtin_amdgcn_rcpf(1.f + __expf(-x));
}

__global__ void __launch_bounds__(TPB) gru_persistent(
    float* __restrict__ hA, float* __restrict__ hB,
    const int* __restrict__ row_ptr, const int* __restrict__ col_idx,
    const float* __restrict__ wgt,
    const float* __restrict__ Wg, const float* __restrict__ bg,
    const float* __restrict__ xr, const float* __restrict__ xz,
    const float* __restrict__ xh,
    float* __restrict__ out,
    unsigned* __restrict__ glvl1, unsigned* __restrict__ groot,
    unsigned* __restrict__ xreg, unsigned* __restrict__ xcnt,
    unsigned* __restrict__ xgo)
{
    __shared__ float aggL[TPB];
    __shared__ int jn[MAXJ], jrs[MAXJ], jraw[MAXJ], jplen[MAXJ], jofs[MAXJ];
    __shared__ __align__(16) int2 eLDS[ECAP];   // (byte-offset, bitcast weight)
    __shared__ int shr_slot, shr_cnt, shr_mode, shr_use;

    const int tid = threadIdx.x;
    const int lane = tid & 63;
    const int wid = tid >> 6;        // wave id (0..7)
    const int half = lane >> 5;      // which batch of the pair
    const int l = lane & 31;         // channel

    // physical XCD id [measured: learn_hip m09]
    int xraw;
    asm volatile("s_getreg_b32 %0, hwreg(HW_REG_XCC_ID)" : "=s"(xraw));
    int xid = xraw & 7;

    if (tid == 0)
        shr_slot = (int)__hip_atomic_fetch_add(&xreg[xid * 32], 1u, __ATOMIC_RELAXED,
                                               __HIP_MEMORY_SCOPE_AGENT);
    __syncthreads();
    int slot = shr_slot;

    global_barrier(glvl1, groot, 1u);   // settle registration

    if (tid == 0) {
        int sum = 0, mode = 1, mycnt = 0;
        for (int xx = 0; xx < NXCD; xx++) {
            int c = (int)__hip_atomic_load(&xreg[xx * 32], __ATOMIC_RELAXED,
                                           __HIP_MEMORY_SCOPE_AGENT);
            sum += c;
            if (c < 32) mode = 0;       // guarantees nodes/wave <= 8 (MAXJ)
            if (xx == xid) mycnt = c;
        }
        if (sum != NBLK) mode = 0;
        shr_mode = mode;
        shr_cnt = mycnt;
    }
    __syncthreads();
    const int xmode = shr_mode;
    int cnt = shr_cnt;
    if (!xmode) { xid = blockIdx.x & 7; slot = blockIdx.x >> 3; cnt = NBLK / NXCD; }
    const int wtot = cnt * 8;

    // ---- per-block node metadata (j = k*8 + waveid) ----
    if (tid < MAXJ) {
        int k = tid >> 3, w = tid & 7;
        int n = slot * 8 + w + k * wtot;
        if (n < NN) {
            int rs = row_ptr[n], re = row_ptr[n + 1];
            jn[tid] = n; jrs[tid] = rs; jraw[tid] = re - rs;
            jplen[tid] = (re - rs + 1) & ~1;            // pad to x2 (int4 granule)
        } else {
            jn[tid] = -1; jrs[tid] = 0; jraw[tid] = 0; jplen[tid] = 0;
        }
    }
    __syncthreads();
    if (tid == 0) {
        int o = 0;
        for (int j = 0; j < MAXJ; j++) { jofs[j] = o; o += jplen[j]; }
        shr_use = (o <= ECAP);
    }
    __syncthreads();
    const bool use_lds = (shr_use != 0);

    // ---- stage edges into LDS once (time-invariant), padded to x2 ----
    if (use_lds) {
        for (int k = 0; k < 8; k++) {
            int j = k * 8 + wid;
            if (jn[j] < 0) break;
            int rs = jrs[j], raw = jraw[j], pl = jplen[j], of = jofs[j];
            for (int i = lane; i < pl; i += 64) {
                int2 v;
                if (i < raw) { v.x = col_idx[rs + i] << 2; v.y = __float_as_int(wgt[rs + i]); }
                else         { v.x = 0; v.y = 0; }
                eLDS[of + i] = v;
            }
        }
    }
    __syncthreads();

    // ---- per-thread constants ----
    const int bb = 2 * xid + half;
    const float xrv = xr[bb * HD + l];
    const float xzv = xz[bb * HD + l];
    const float xhv = xh[bb * HD + l];
    const float bgv = bg[l];
    float wgreg[HD];
#pragma unroll
    for (int k = 0; k < HD; k++) wgreg[k] = Wg[k * HD + l];

    const int hoffb = (bb * (NN * HD) + l) * 4;         // byte offset of this thread's lane
    float* outp = out + (size_t)bb * SEQ * (NN * HD) + l;

    const char* hprev = (const char*)hA;
    char* hnext = (char*)hB;

    // ---- t = 0: state is identically zero -> no gather, no matvec, no h-read ----
    {
        const float conv = bgv;
        const float r = fast_sigmoid(xrv + conv);
        const float z = fast_sigmoid(xzv + conv);
        const float e2 = __expf(2.f * (xhv + r * conv));
        const float ht = 1.f - 2.f * __builtin_amdgcn_rcpf(e2 + 1.f);
        const float hn = z * ht;                        // hp = 0
        for (int k = 0; k < 8; k++) {
            const int n = jn[k * 8 + wid];
            if (n < 0) break;
            *(float*)(hnext + (hoffb + (n << 7))) = hn;
            __builtin_nontemporal_store(hn, outp + (n << 5));
        }
    }
    if (xmode) xcd_barrier(xcnt, xgo, xid, slot, cnt, 1u);
    else       global_barrier(glvl1, groot, 2u);
    { char* tmp = (char*)hprev; hprev = hnext; hnext = tmp; }
    outp += NN * HD;

    for (int t = 1; t < SEQ; t++) {
        for (int k = 0; k < 8; k++) {
            const int j = k * 8 + wid;
            const int n = jn[j];
            if (n < 0) break;

            float agg = 0.f;
            if (use_lds) {
                const int4* ep = (const int4*)&eLDS[jofs[j]];   // 2 edges per int4
                const int pl = jplen[j];
                int e = 0;
                // 16 edges per iteration: 16 independent loads in flight
                for (; e + 16 <= pl; e += 16) {
                    int4 p0 = ep[0], p1 = ep[1], p2 = ep[2], p3 = ep[3];
                    int4 p4 = ep[4], p5 = ep[5], p6 = ep[6], p7 = ep[7];
                    ep += 8;
                    float v0 = *(const float*)(hprev + (hoffb + p0.x));
                    float v1 = *(const float*)(hprev + (hoffb + p0.z));
                    float v2 = *(const float*)(hprev + (hoffb + p1.x));
                    float v3 = *(const float*)(hprev + (hoffb + p1.z));
                    float v4 = *(const float*)(hprev + (hoffb + p2.x));
                    float v5 = *(const float*)(hprev + (hoffb + p2.z));
                    float v6 = *(const float*)(hprev + (hoffb + p3.x));
                    float v7 = *(const float*)(hprev + (hoffb + p3.z));
                    float v8 = *(const float*)(hprev + (hoffb + p4.x));
                    float v9 = *(const float*)(hprev + (hoffb + p4.z));
                    float va = *(const float*)(hprev + (hoffb + p5.x));
                    float vb = *(const float*)(hprev + (hoffb + p5.z));
                    float vc = *(const float*)(hprev + (hoffb + p6.x));
                    float vd = *(const float*)(hprev + (hoffb + p6.z));
                    float ve = *(const float*)(hprev + (hoffb + p7.x));
                    float vf = *(const float*)(hprev + (hoffb + p7.z));
                    agg = fmaf(__int_as_float(p0.y), v0, agg);
                    agg = fmaf(__int_as_float(p0.w), v1, agg);
                    agg = fmaf(__int_as_float(p1.y), v2, agg);
                    agg = fmaf(__int_as_float(p1.w), v3, agg);
                    agg = fmaf(__int_as_float(p2.y), v4, agg);
                    agg = fmaf(__int_as_float(p2.w), v5, agg);
                    agg = fmaf(__int_as_float(p3.y), v6, agg);
                    agg = fmaf(__int_as_float(p3.w), v7, agg);
                    agg = fmaf(__int_as_float(p4.y), v8, agg);
                    agg = fmaf(__int_as_float(p4.w), v9, agg);
                    agg = fmaf(__int_as_float(p5.y), va, agg);
                    agg = fmaf(__int_as_float(p5.w), vb, agg);
                    agg = fmaf(__int_as_float(p6.y), vc, agg);
                    agg = fmaf(__int_as_float(p6.w), vd, agg);
                    agg = fmaf(__int_as_float(p7.y), ve, agg);
                    agg = fmaf(__int_as_float(p7.w), vf, agg);
                }
                for (; e < pl; e += 2) {                 // 2-edge tail granules
                    int4 p0 = *ep++;
                    float v0 = *(const float*)(hprev + (hoffb + p0.x));
                    float v1 = *(const float*)(hprev + (hoffb + p0.z));
                    agg = fmaf(__int_as_float(p0.y), v0, agg);
                    agg = fmaf(__int_as_float(p0.w), v1, agg);
                }
            } else {   // rare overflow path: stream from global
                const int rs = jrs[j], re = rs + jraw[j];
                for (int e = rs; e < re; e++) {
                    int cb = col_idx[e] << 2;
                    agg = fmaf(wgt[e], *(const float*)(hprev + (hoffb + cb)), agg);
                }
            }

            // matvec: conv[l] = bg[l] + sum_k agg[k] * Wg[k][l]
            // per-wave LDS broadcast (writer wave == reader wave -> lockstep)
            aggL[tid] = agg;
            const float4* arow = (const float4*)&aggL[(tid & ~63) + (half << 5)];
            float conv = bgv;
#pragma unroll
            for (int kq = 0; kq < 8; kq++) {
                float4 a4 = arow[kq];
                conv = fmaf(a4.x, wgreg[4 * kq + 0], conv);
                conv = fmaf(a4.y, wgreg[4 * kq + 1], conv);
                conv = fmaf(a4.z, wgreg[4 * kq + 2], conv);
                conv = fmaf(a4.w, wgreg[4 * kq + 3], conv);
            }

            const float r = fast_sigmoid(xrv + conv);
            const float z = fast_sigmoid(xzv + conv);
            const float e2 = __expf(2.f * (xhv + r * conv));
            const float ht = 1.f - 2.f * __builtin_amdgcn_rcpf(e2 + 1.f);
            const int nb = hoffb + (n << 7);             // node byte offset
            const float hp = *(const float*)(hprev + nb);
            const float hn = fmaf(z, ht - hp, hp);

            *(float*)(hnext + nb) = hn;
            __builtin_nontemporal_store(hn, outp + (n << 5));
        }
        if (t != SEQ - 1) {
            if (xmode) xcd_barrier(xcnt, xgo, xid, slot, cnt, (unsigned)(t + 1));
            else       global_barrier(glvl1, groot, (unsigned)(t + 2));
        }
        char* tmp = (char*)hprev; hprev = hnext; hnext = tmp;
        outp += NN * HD;
    }
}

// ---------------- launch ----------------

extern "C" void kernel_launch(void* const* d_in, const int* in_sizes, int n_in,
                              void* d_out, int out_size, void* d_ws, size_t ws_size,
                              hipStream_t stream) {
    const float* x   = (const float*)d_in[0];
    const int*   src = (const int*)d_in[1];
    const int*   dst = (const int*)d_in[2];
    const float* Wr  = (const float*)d_in[3];
    const float* br  = (const float*)d_in[4];
    const float* Wz  = (const float*)d_in[5];
    const float* bz  = (const float*)d_in[6];
    const float* Wh  = (const float*)d_in[7];
    const float* bh  = (const float*)d_in[8];
    const float* Wg  = (const float*)d_in[9];
    const float* bg  = (const float*)d_in[10];
    float* out = (float*)d_out;

    char* ws = (char*)d_ws;
    float* h0 = (float*)ws;            ws += (size_t)BATCH * NN * HD * 4;
    float* h1 = (float*)ws;            ws += (size_t)BATCH * NN * HD * 4;
    float* xr = (float*)ws;            ws += BATCH * HD * 4;
    float* xz = (float*)ws;            ws += BATCH * HD * 4;
    float* xh = (float*)ws;            ws += BATCH * HD * 4;
    int* deg_out = (int*)ws;           ws += NN * 4;
    int* deg_in  = (int*)ws;           ws += NN * 4;
    int* cursor  = (int*)ws;           ws += NN * 4;
    int* row_ptr = (int*)ws;           ws += (NN + 1) * 4;
    int* col_idx = (int*)ws;           ws += NE * 4;
    float* wgt   = (float*)ws;         ws += NE * 4;
    unsigned* glvl1 = (unsigned*)ws;   ws += NGRP * 32 * 4;
    unsigned* groot = (unsigned*)ws;   ws += 32 * 4;
    unsigned* xreg  = (unsigned*)ws;   ws += NXCD * 32 * 4;
    unsigned* xcnt  = (unsigned*)ws;   ws += NXCD * 8 * 32 * 4;
    unsigned* xgo   = (unsigned*)ws;   ws += NXCD * 32 * 4;

    // t=0 shortcut never reads h -> no h memset needed; only barrier counters.
    hipMemsetAsync(deg_out, 0, 3 * NN * 4, stream);
    hipMemsetAsync(glvl1, 0,
                   (NGRP * 32 + 32 + NXCD * 32 + NXCD * 8 * 32 + NXCD * 32) * 4, stream);

    count_deg<<<NE / 256, 256, 0, stream>>>(src, dst, deg_out, deg_in);
    scan_rowptr<<<1, 256, 0, stream>>>(deg_in, row_ptr);
    scatter_edges<<<NE / 256, 256, 0, stream>>>(src, dst, deg_out, deg_in, row_ptr,
                                                cursor, col_idx, wgt);
    xgates<<<2, 256, 0, stream>>>(x, Wr, br, Wz, bz, Wh, bh, xr, xz, xh);

    gru_persistent<<<dim3(NBLK), dim3(TPB), 0, stream>>>(
        h0, h1, row_ptr, col_idx, wgt, Wg, bg, xr, xz, xh, out,
        glvl1, groot, xreg, xcnt, xgo);
}

// Round 13
// 771.014 us; speedup vs baseline: 1.2464x; 1.1597x over previous
//
#include <hip/hip_runtime.h>
#include <math.h>

#define BATCH 16
#define IN 128
#define HD 32
#define NN 2048
#define NE 32768
#define SEQ 100
#define TPB 512
#define NBLK 512            // 2 blocks/CU -- PROVEN co-resident (rounds 6-10); do not raise
#define GSZ 32              // global barrier: blocks per group
#define NGRP (NBLK / GSZ)   // 16
#define NXCD 8
#define MAXJ 64             // max (k,wave) node slots per block
#define ECAP 1536           // LDS edge cache entries (int2, 12 KB)

// ---------------- preprocessing ----------------

__global__ void count_deg(const int* __restrict__ src, const int* __restrict__ dst,
                          int* deg_out, int* deg_in) {
    int e = blockIdx.x * blockDim.x + threadIdx.x;
    if (e < NE) {
        atomicAdd(&deg_out[src[e]], 1);
        atomicAdd(&deg_in[dst[e]], 1);
    }
}

__global__ void scan_rowptr(const int* __restrict__ deg_in, int* __restrict__ row_ptr) {
    __shared__ int partial[256];
    int t = threadIdx.x;
    int base = t * 8;
    int vals[8];
    int s = 0;
    for (int j = 0; j < 8; j++) { vals[j] = deg_in[base + j]; s += vals[j]; }
    partial[t] = s;
    __syncthreads();
    if (t == 0) {
        int acc = 0;
        for (int i = 0; i < 256; i++) { int v = partial[i]; partial[i] = acc; acc += v; }
        row_ptr[NN] = acc;
    }
    __syncthreads();
    int acc = partial[t];
    for (int j = 0; j < 8; j++) { row_ptr[base + j] = acc; acc += vals[j]; }
}

// col_idx stores src*HD (element offset of the source node's row)
__global__ void scatter_edges(const int* __restrict__ src, const int* __restrict__ dst,
                              const int* __restrict__ deg_out, const int* __restrict__ deg_in,
                              const int* __restrict__ row_ptr, int* __restrict__ cursor,
                              int* __restrict__ col_idx, float* __restrict__ wgt) {
    int e = blockIdx.x * blockDim.x + threadIdx.x;
    if (e < NE) {
        int s = src[e], d = dst[e];
        int pos = row_ptr[d] + atomicAdd(&cursor[d], 1);
        col_idx[pos] = s * HD;
        float doo = (float)max(deg_out[s], 1);
        float dii = (float)max(deg_in[d], 1);
        wgt[pos] = rsqrtf(doo * dii);
    }
}

__global__ void xgates(const float* __restrict__ x,
                       const float* __restrict__ Wr, const float* __restrict__ br,
                       const float* __restrict__ Wz, const float* __restrict__ bz,
                       const float* __restrict__ Wh, const float* __restrict__ bh,
                       float* __restrict__ xr, float* __restrict__ xz, float* __restrict__ xh) {
    int t = blockIdx.x * blockDim.x + threadIdx.x;
    if (t < BATCH * HD) {
        int b = t / HD, hh = t % HD;
        float ar = br[hh], az = bz[hh], ah = bh[hh];
        const float* xb = x + b * IN;
        for (int i = 0; i < IN; i++) {
            float xv = xb[i];
            ar += xv * Wr[i * HD + hh];
            az += xv * Wz[i * HD + hh];
            ah += xv * Wh[i * HD + hh];
        }
        xr[t] = ar; xz[t] = az; xh[t] = ah;
    }
}

// ---------------- barriers ----------------

// Global two-level barrier with agent fences (proven round 6).
__device__ __forceinline__ void global_barrier(unsigned* __restrict__ lvl1,
                                               unsigned* __restrict__ root,
                                               unsigned step) {
    __syncthreads();
    if (threadIdx.x == 0) {
        const int gid = blockIdx.x / GSZ;
        __builtin_amdgcn_fence(__ATOMIC_RELEASE, "agent");
        __hip_atomic_fetch_add(&lvl1[gid * 32], 1u, __ATOMIC_RELAXED,
                               __HIP_MEMORY_SCOPE_AGENT);
        if ((blockIdx.x % GSZ) == 0) {
            while (__hip_atomic_load(&lvl1[gid * 32], __ATOMIC_RELAXED,
                                     __HIP_MEMORY_SCOPE_AGENT) < GSZ * step)
                __builtin_amdgcn_s_sleep(2);
            __hip_atomic_fetch_add(root, 1u, __ATOMIC_RELAXED,
                                   __HIP_MEMORY_SCOPE_AGENT);
        }
        while (__hip_atomic_load(root, __ATOMIC_RELAXED,
                                 __HIP_MEMORY_SCOPE_AGENT) < NGRP * step)
            __builtin_amdgcn_s_sleep(2);
        __builtin_amdgcn_fence(__ATOMIC_ACQUIRE, "agent");
    }
    __syncthreads();
}

// Per-XCD barrier (proven rounds 7-10). Arrivals spread over 8 cache lines
// (slot&7); leader polls the 8-line sum (monotonic counters -> race-free).
__device__ __forceinline__ void xcd_barrier(unsigned* __restrict__ xcnt,
                                            unsigned* __restrict__ xgo,
                                            int xid, int slot, int cnt, unsigned s) {
    __syncthreads();
    if (threadIdx.x == 0) {
        __hip_atomic_fetch_add(&xcnt[(xid * 8 + (slot & 7)) * 32], 1u,
                               __ATOMIC_RELAXED, __HIP_MEMORY_SCOPE_AGENT);
        if (slot == 0) {
            for (;;) {
                unsigned sum = 0;
#pragma unroll
                for (int i = 0; i < 8; i++)
                    sum += __hip_atomic_load(&xcnt[(xid * 8 + i) * 32],
                                             __ATOMIC_RELAXED, __HIP_MEMORY_SCOPE_AGENT);
                if (sum >= (unsigned)cnt * s) break;
                __builtin_amdgcn_s_sleep(1);
            }
            __hip_atomic_store(&xgo[xid * 32], s, __ATOMIC_RELAXED,
                               __HIP_MEMORY_SCOPE_AGENT);
        } else {
            while (__hip_atomic_load(&xgo[xid * 32], __ATOMIC_RELAXED,
                                     __HIP_MEMORY_SCOPE_AGENT) < s)
                __builtin_amdgcn_s_sleep(1);
        }
    }
    __syncthreads();
    asm volatile("buffer_inv sc0\n\ts_waitcnt vmcnt(0)" ::: "memory");
}

// ---------------- persistent kernel ----------------
// h layout: [B][N][H] in a compact 4MB double buffer (L2-resident; round 11
// proved using `out` as state costs 200MB of HBM re-fetch).
// Wave = one node for a batch PAIR: lanes 0-31 -> batch b0, lanes 32-63 -> b0+1.
// k-slots are processed in PAIRS (k,k+1) with interleaved gathers so one
// node's FMAs cover the other's load latency (round 12 lesson: in-flight
// loads beat op-count savings).

__device__ __forceinline__ float fast_sigmoid(float x) {
    return __builtin_amdgcn_rcpf(1.f + __expf(-x));
}

// matvec + gates + state/out stores for one node, given its gather result
__device__ __forceinline__ void finish_node(
    int tid, int half, float agg, float* __restrict__ aggbuf,
    const float* __restrict__ wgreg, float bgv,
    float xrv, float xzv, float xhv,
    const char* __restrict__ hprev, char* __restrict__ hnext,
    int hoffb, float* __restrict__ outp, int n)
{
    aggbuf[tid] = agg;
    const float4* arow = (const float4*)&aggbuf[(tid & ~63) + (half << 5)];
    float conv = bgv;
#pragma unroll
    for (int kq = 0; kq < 8; kq++) {
        float4 a4 = arow[kq];
        conv = fmaf(a4.x, wgreg[4 * kq + 0], conv);
        conv = fmaf(a4.y, wgreg[4 * kq + 1], conv);
        conv = fmaf(a4.z, wgreg[4 * kq + 2], conv);
        conv = fmaf(a4.w, wgreg[4 * kq + 3], conv);
    }
    const float r = fast_sigmoid(xrv + conv);
    const float z = fast_sigmoid(xzv + conv);
    const float e2 = __expf(2.f * (xhv + r * conv));
    const float ht = 1.f - 2.f * __builtin_amdgcn_rcpf(e2 + 1.f);
    const int nb = hoffb + (n << 7);
    const float hp = *(const float*)(hprev + nb);
    const float hn = fmaf(z, ht - hp, hp);
    *(float*)(hnext + nb) = hn;
    __builtin_nontemporal_store(hn, outp + (n << 5));
}

__global__ void __launch_bounds__(TPB, 4) gru_persistent(
    float* __restrict__ hA, float* __restrict__ hB,
    const int* __restrict__ row_ptr, const int* __restrict__ col_idx,
    const float* __restrict__ wgt,
    const float* __restrict__ Wg, const float* __restrict__ bg,
    const float* __restrict__ xr, const float* __restrict__ xz,
    const float* __restrict__ xh,
    float* __restrict__ out,
    unsigned* __restrict__ glvl1, unsigned* __restrict__ groot,
    unsigned* __restrict__ xreg, unsigned* __restrict__ xcnt,
    unsigned* __restrict__ xgo)
{
    __shared__ float aggL[2 * TPB];
    __shared__ int jn[MAXJ], jrs[MAXJ], jraw[MAXJ], jplen[MAXJ], jofs[MAXJ];
    __shared__ __align__(16) int2 eLDS[ECAP];   // (byte-offset, bitcast weight)
    __shared__ int shr_slot, shr_cnt, shr_mode, shr_use;

    const int tid = threadIdx.x;
    const int lane = tid & 63;
    const int wid = tid >> 6;        // wave id (0..7)
    const int half = lane >> 5;      // which batch of the pair
    const int l = lane & 31;         // channel

    // physical XCD id [measured: learn_hip m09]
    int xraw;
    asm volatile("s_getreg_b32 %0, hwreg(HW_REG_XCC_ID)" : "=s"(xraw));
    int xid = xraw & 7;

    if (tid == 0)
        shr_slot = (int)__hip_atomic_fetch_add(&xreg[xid * 32], 1u, __ATOMIC_RELAXED,
                                               __HIP_MEMORY_SCOPE_AGENT);
    __syncthreads();
    int slot = shr_slot;

    global_barrier(glvl1, groot, 1u);   // settle registration

    if (tid == 0) {
        int sum = 0, mode = 1, mycnt = 0;
        for (int xx = 0; xx < NXCD; xx++) {
            int c = (int)__hip_atomic_load(&xreg[xx * 32], __ATOMIC_RELAXED,
                                           __HIP_MEMORY_SCOPE_AGENT);
            sum += c;
            if (c < 32) mode = 0;       // guarantees nodes/wave <= 8 (MAXJ)
            if (xx == xid) mycnt = c;
        }
        if (sum != NBLK) mode = 0;
        shr_mode = mode;
        shr_cnt = mycnt;
    }
    __syncthreads();
    const int xmode = shr_mode;
    int cnt = shr_cnt;
    if (!xmode) { xid = blockIdx.x & 7; slot = blockIdx.x >> 3; cnt = NBLK / NXCD; }
    const int wtot = cnt * 8;

    // ---- per-block node metadata (j = k*8 + waveid) ----
    if (tid < MAXJ) {
        int k = tid >> 3, w = tid & 7;
        int n = slot * 8 + w + k * wtot;
        if (n < NN) {
            int rs = row_ptr[n], re = row_ptr[n + 1];
            jn[tid] = n; jrs[tid] = rs; jraw[tid] = re - rs;
            jplen[tid] = (re - rs + 7) & ~7;            // pad to x8 (proven)
        } else {
            jn[tid] = -1; jrs[tid] = 0; jraw[tid] = 0; jplen[tid] = 0;
        }
    }
    __syncthreads();
    // equalize padded length within each (k, k+1) pair so the paired gather
    // loop has a single trip count (tid^8 flips the k-parity bit)
    int pmax = 0;
    if (tid < MAXJ) pmax = max(jplen[tid], jplen[tid ^ 8]);
    __syncthreads();
    if (tid < MAXJ && jn[tid] >= 0) jplen[tid] = pmax;
    __syncthreads();
    if (tid == 0) {
        int o = 0;
        for (int j = 0; j < MAXJ; j++) { jofs[j] = o; o += jplen[j]; }
        shr_use = (o <= ECAP);
    }
    __syncthreads();
    const bool use_lds = (shr_use != 0);

    // ---- stage edges into LDS once (time-invariant), zero-padded ----
    if (use_lds) {
        for (int k = 0; k < 8; k++) {
            int j = k * 8 + wid;
            if (jn[j] < 0) break;
            int rs = jrs[j], raw = jraw[j], pl = jplen[j], of = jofs[j];
            for (int i = lane; i < pl; i += 64) {
                int2 v;
                if (i < raw) { v.x = col_idx[rs + i] << 2; v.y = __float_as_int(wgt[rs + i]); }
                else         { v.x = 0; v.y = 0; }
                eLDS[of + i] = v;
            }
        }
    }
    __syncthreads();

    // ---- per-thread constants ----
    const int bb = 2 * xid + half;
    const float xrv = xr[bb * HD + l];
    const float xzv = xz[bb * HD + l];
    const float xhv = xh[bb * HD + l];
    const float bgv = bg[l];
    float wgreg[HD];
#pragma unroll
    for (int k = 0; k < HD; k++) wgreg[k] = Wg[k * HD + l];

    const int hoffb = (bb * (NN * HD) + l) * 4;         // byte offset of this thread's lane
    float* outp = out + (size_t)bb * SEQ * (NN * HD) + l;

    const char* hprev = (const char*)hA;
    char* hnext = (char*)hB;

    // ---- t = 0: state is identically zero -> no gather, no matvec, no h-read ----
    {
        const float conv = bgv;
        const float r = fast_sigmoid(xrv + conv);
        const float z = fast_sigmoid(xzv + conv);
        const float e2 = __expf(2.f * (xhv + r * conv));
        const float ht = 1.f - 2.f * __builtin_amdgcn_rcpf(e2 + 1.f);
        const float hn = z * ht;                        // hp = 0
        for (int k = 0; k < 8; k++) {
            const int n = jn[k * 8 + wid];
            if (n < 0) break;
            *(float*)(hnext + (hoffb + (n << 7))) = hn;
            __builtin_nontemporal_store(hn, outp + (n << 5));
        }
    }
    if (xmode) xcd_barrier(xcnt, xgo, xid, slot, cnt, 1u);
    else       global_barrier(glvl1, groot, 2u);
    { char* tmp = (char*)hprev; hprev = hnext; hnext = tmp; }
    outp += NN * HD;

    for (int t = 1; t < SEQ; t++) {
        if (use_lds) {
            for (int kp = 0; kp < 8; kp += 2) {
                const int jA = kp * 8 + wid;
                const int jB = jA + 8;
                const int nA = jn[jA];
                if (nA < 0) break;
                const int nB = jn[jB];

                if (nB >= 0) {
                    // ---- paired gather: A and B interleaved, equal trip count ----
                    const int4* epA = (const int4*)&eLDS[jofs[jA]];
                    const int4* epB = (const int4*)&eLDS[jofs[jB]];
                    const int pl = jplen[jA];           // == jplen[jB]
                    float aggA = 0.f, aggB = 0.f;
                    for (int e = 0; e < pl; e += 8) {
                        int4 a0 = epA[0], a1 = epA[1], a2 = epA[2], a3 = epA[3];
                        int4 b0 = epB[0], b1 = epB[1], b2 = epB[2], b3 = epB[3];
                        epA += 4; epB += 4;
                        float va0 = *(const float*)(hprev + (hoffb + a0.x));
                        float va1 = *(const float*)(hprev + (hoffb + a0.z));
                        float va2 = *(const float*)(hprev + (hoffb + a1.x));
                        float va3 = *(const float*)(hprev + (hoffb + a1.z));
                        float va4 = *(const float*)(hprev + (hoffb + a2.x));
                        float va5 = *(const float*)(hprev + (hoffb + a2.z));
                        float va6 = *(const float*)(hprev + (hoffb + a3.x));
                        float va7 = *(const float*)(hprev + (hoffb + a3.z));
                        float vb0 = *(const float*)(hprev + (hoffb + b0.x));
                        float vb1 = *(const float*)(hprev + (hoffb + b0.z));
                        float vb2 = *(const float*)(hprev + (hoffb + b1.x));
                        float vb3 = *(const float*)(hprev + (hoffb + b1.z));
                        float vb4 = *(const float*)(hprev + (hoffb + b2.x));
                        float vb5 = *(const float*)(hprev + (hoffb + b2.z));
                        float vb6 = *(const float*)(hprev + (hoffb + b3.x));
                        float vb7 = *(const float*)(hprev + (hoffb + b3.z));
                        aggA = fmaf(__int_as_float(a0.y), va0, aggA);
                        aggA = fmaf(__int_as_float(a0.w), va1, aggA);
                        aggA = fmaf(__int_as_float(a1.y), va2, aggA);
                        aggA = fmaf(__int_as_float(a1.w), va3, aggA);
                        aggA = fmaf(__int_as_float(a2.y), va4, aggA);
                        aggA = fmaf(__int_as_float(a2.w), va5, aggA);
                        aggA = fmaf(__int_as_float(a3.y), va6, aggA);
                        aggA = fmaf(__int_as_float(a3.w), va7, aggA);
                        aggB = fmaf(__int_as_float(b0.y), vb0, aggB);
                        aggB = fmaf(__int_as_float(b0.w), vb1, aggB);
                        aggB = fmaf(__int_as_float(b1.y), vb2, aggB);
                        aggB = fmaf(__int_as_float(b1.w), vb3, aggB);
                        aggB = fmaf(__int_as_float(b2.y), vb4, aggB);
                        aggB = fmaf(__int_as_float(b2.w), vb5, aggB);
                        aggB = fmaf(__int_as_float(b3.y), vb6, aggB);
                        aggB = fmaf(__int_as_float(b3.w), vb7, aggB);
                    }

                    // ---- paired matvec (interleaved LDS reads + FMAs) ----
                    aggL[tid] = aggA;
                    aggL[TPB + tid] = aggB;
                    const int abase = (tid & ~63) + (half << 5);
                    const float4* arA = (const float4*)&aggL[abase];
                    const float4* arB = (const float4*)&aggL[TPB + abase];
                    float convA = bgv, convB = bgv;
#pragma unroll
                    for (int kq = 0; kq < 8; kq++) {
                        float4 a4 = arA[kq];
                        float4 b4 = arB[kq];
                        convA = fmaf(a4.x, wgreg[4 * kq + 0], convA);
                        convA = fmaf(a4.y, wgreg[4 * kq + 1], convA);
                        convA = fmaf(a4.z, wgreg[4 * kq + 2], convA);
                        convA = fmaf(a4.w, wgreg[4 * kq + 3], convA);
                        convB = fmaf(b4.x, wgreg[4 * kq + 0], convB);
                        convB = fmaf(b4.y, wgreg[4 * kq + 1], convB);
                        convB = fmaf(b4.z, wgreg[4 * kq + 2], convB);
                        convB = fmaf(b4.w, wgreg[4 * kq + 3], convB);
                    }

                    // ---- gates + stores (A and B independent) ----
                    const float rA = fast_sigmoid(xrv + convA);
                    const float zA = fast_sigmoid(xzv + convA);
                    const float rB = fast_sigmoid(xrv + convB);
                    const float zB = fast_sigmoid(xzv + convB);
                    const float eA = __expf(2.f * (xhv + rA * convA));
                    const float eB = __expf(2.f * (xhv + rB * convB));
                    const float htA = 1.f - 2.f * __builtin_amdgcn_rcpf(eA + 1.f);
                    const float htB = 1.f - 2.f * __builtin_amdgcn_rcpf(eB + 1.f);
                    const int nbA = hoffb + (nA << 7);
                    const int nbB = hoffb + (nB << 7);
                    const float hpA = *(const float*)(hprev + nbA);
                    const float hpB = *(const float*)(hprev + nbB);
                    const float hnA = fmaf(zA, htA - hpA, hpA);
                    const float hnB = fmaf(zB, htB - hpB, hpB);
                    *(float*)(hnext + nbA) = hnA;
                    *(float*)(hnext + nbB) = hnB;
                    __builtin_nontemporal_store(hnA, outp + (nA << 5));
                    __builtin_nontemporal_store(hnB, outp + (nB << 5));
                } else {
                    // ---- single trailing node (round-10 16/8 chunking) ----
                    const int4* ep = (const int4*)&eLDS[jofs[jA]];
                    const int pl = jplen[jA];
                    float agg = 0.f;
                    int e = 0;
                    for (; e + 16 <= pl; e += 16) {
                        int4 p0 = ep[0], p1 = ep[1], p2 = ep[2], p3 = ep[3];
                        int4 p4 = ep[4], p5 = ep[5], p6 = ep[6], p7 = ep[7];
                        ep += 8;
                        float v0 = *(const float*)(hprev + (hoffb + p0.x));
                        float v1 = *(const float*)(hprev + (hoffb + p0.z));
                        float v2 = *(const float*)(hprev + (hoffb + p1.x));
                        float v3 = *(const float*)(hprev + (hoffb + p1.z));
                        float v4 = *(const float*)(hprev + (hoffb + p2.x));
                        float v5 = *(const float*)(hprev + (hoffb + p2.z));
                        float v6 = *(const float*)(hprev + (hoffb + p3.x));
                        float v7 = *(const float*)(hprev + (hoffb + p3.z));
                        float v8 = *(const float*)(hprev + (hoffb + p4.x));
                        float v9 = *(const float*)(hprev + (hoffb + p4.z));
                        float va = *(const float*)(hprev + (hoffb + p5.x));
                        float vb = *(const float*)(hprev + (hoffb + p5.z));
                        float vc = *(const float*)(hprev + (hoffb + p6.x));
                        float vd = *(const float*)(hprev + (hoffb + p6.z));
                        float ve = *(const float*)(hprev + (hoffb + p7.x));
                        float vf = *(const float*)(hprev + (hoffb + p7.z));
                        agg = fmaf(__int_as_float(p0.y), v0, agg);
                        agg = fmaf(__int_as_float(p0.w), v1, agg);
                        agg = fmaf(__int_as_float(p1.y), v2, agg);
                        agg = fmaf(__int_as_float(p1.w), v3, agg);
                        agg = fmaf(__int_as_float(p2.y), v4, agg);
                        agg = fmaf(__int_as_float(p2.w), v5, agg);
                        agg = fmaf(__int_as_float(p3.y), v6, agg);
                        agg = fmaf(__int_as_float(p3.w), v7, agg);
                        agg = fmaf(__int_as_float(p4.y), v8, agg);
                        agg = fmaf(__int_as_float(p4.w), v9, agg);
                        agg = fmaf(__int_as_float(p5.y), va, agg);
                        agg = fmaf(__int_as_float(p5.w), vb, agg);
                        agg = fmaf(__int_as_float(p6.y), vc, agg);
                        agg = fmaf(__int_as_float(p6.w), vd, agg);
                        agg = fmaf(__int_as_float(p7.y), ve, agg);
                        agg = fmaf(__int_as_float(p7.w), vf, agg);
                    }
                    if (e < pl) {   // pl multiple of 8 -> at most one 8-chunk tail
                        int4 p0 = ep[0], p1 = ep[1], p2 = ep[2], p3 = ep[3];
                        float v0 = *(const float*)(hprev + (hoffb + p0.x));
                        float v1 = *(const float*)(hprev + (hoffb + p0.z));
                        float v2 = *(const float*)(hprev + (hoffb + p1.x));
                        float v3 = *(const float*)(hprev + (hoffb + p1.z));
                        float v4 = *(const float*)(hprev + (hoffb + p2.x));
                        float v5 = *(const float*)(hprev + (hoffb + p2.z));
                        float v6 = *(const float*)(hprev + (hoffb + p3.x));
                        float v7 = *(const float*)(hprev + (hoffb + p3.z));
                        agg = fmaf(__int_as_float(p0.y), v0, agg);
                        agg = fmaf(__int_as_float(p0.w), v1, agg);
                        agg = fmaf(__int_as_float(p1.y), v2, agg);
                        agg = fmaf(__int_as_float(p1.w), v3, agg);
                        agg = fmaf(__int_as_float(p2.y), v4, agg);
                        agg = fmaf(__int_as_float(p2.w), v5, agg);
                        agg = fmaf(__int_as_float(p3.y), v6, agg);
                        agg = fmaf(__int_as_float(p3.w), v7, agg);
                    }
                    finish_node(tid, half, agg, aggL, wgreg, bgv, xrv, xzv, xhv,
                                hprev, hnext, hoffb, outp, nA);
                }
            }
        } else {
            // rare overflow path: stream edge lists from global, node by node
            for (int k = 0; k < 8; k++) {
                const int j = k * 8 + wid;
                const int n = jn[j];
                if (n < 0) break;
                float agg = 0.f;
                const int rs = jrs[j], re = rs + jraw[j];
                for (int e = rs; e < re; e++) {
                    int cb = col_idx[e] << 2;
                    agg = fmaf(wgt[e], *(const float*)(hprev + (hoffb + cb)), agg);
                }
                finish_node(tid, half, agg, aggL, wgreg, bgv, xrv, xzv, xhv,
                            hprev, hnext, hoffb, outp, n);
            }
        }

        if (t != SEQ - 1) {
            if (xmode) xcd_barrier(xcnt, xgo, xid, slot, cnt, (unsigned)(t + 1));
            else       global_barrier(glvl1, groot, (unsigned)(t + 2));
        }
        char* tmp = (char*)hprev; hprev = hnext; hnext = tmp;
        outp += NN * HD;
    }
}

// ---------------- launch ----------------

extern "C" void kernel_launch(void* const* d_in, const int* in_sizes, int n_in,
                              void* d_out, int out_size, void* d_ws, size_t ws_size,
                              hipStream_t stream) {
    const float* x   = (const float*)d_in[0];
    const int*   src = (const int*)d_in[1];
    const int*   dst = (const int*)d_in[2];
    const float* Wr  = (const float*)d_in[3];
    const float* br  = (const float*)d_in[4];
    const float* Wz  = (const float*)d_in[5];
    const float* bz  = (const float*)d_in[6];
    const float* Wh  = (const float*)d_in[7];
    const float* bh  = (const float*)d_in[8];
    const float* Wg  = (const float*)d_in[9];
    const float* bg  = (const float*)d_in[10];
    float* out = (float*)d_out;

    char* ws = (char*)d_ws;
    float* h0 = (float*)ws;            ws += (size_t)BATCH * NN * HD * 4;
    float* h1 = (float*)ws;            ws += (size_t)BATCH * NN * HD * 4;
    float* xr = (float*)ws;            ws += BATCH * HD * 4;
    float* xz = (float*)ws;            ws += BATCH * HD * 4;
    float* xh = (float*)ws;            ws += BATCH * HD * 4;
    int* deg_out = (int*)ws;           ws += NN * 4;
    int* deg_in  = (int*)ws;           ws += NN * 4;
    int* cursor  = (int*)ws;           ws += NN * 4;
    int* row_ptr = (int*)ws;           ws += (NN + 1) * 4;
    int* col_idx = (int*)ws;           ws += NE * 4;
    float* wgt   = (float*)ws;         ws += NE * 4;
    unsigned* glvl1 = (unsigned*)ws;   ws += NGRP * 32 * 4;
    unsigned* groot = (unsigned*)ws;   ws += 32 * 4;
    unsigned* xreg  = (unsigned*)ws;   ws += NXCD * 32 * 4;
    unsigned* xcnt  = (unsigned*)ws;   ws += NXCD * 8 * 32 * 4;
    unsigned* xgo   = (unsigned*)ws;   ws += NXCD * 32 * 4;

    // t=0 shortcut never reads h -> no h memset needed; only barrier counters.
    hipMemsetAsync(deg_out, 0, 3 * NN * 4, stream);
    hipMemsetAsync(glvl1, 0,
                   (NGRP * 32 + 32 + NXCD * 32 + NXCD * 8 * 32 + NXCD * 32) * 4, stream);

    count_deg<<<NE / 256, 256, 0, stream>>>(src, dst, deg_out, deg_in);
    scan_rowptr<<<1, 256, 0, stream>>>(deg_in, row_ptr);
    scatter_edges<<<NE / 256, 256, 0, stream>>>(src, dst, deg_out, deg_in, row_ptr,
                                                cursor, col_idx, wgt);
    xgates<<<2, 256, 0, stream>>>(x, Wr, br, Wz, bz, Wh, bh, xr, xz, xh);

    gru_persistent<<<dim3(NBLK), dim3(TPB), 0, stream>>>(
        h0, h1, row_ptr, col_idx, wgt, Wg, bg, xr, xz, xh, out,
        glvl1, groot, xreg, xcnt, xgo);
}